// Round 1
// baseline (4901.481 us; speedup 1.0000x reference)
//
#include <hip/hip_runtime.h>
#include <cstddef>
#include <cstdint>

// Shapes fixed by reference setup_inputs():
#define T_LEN 2048
#define B_SZ  32
#define D_SZ  512
#define BD    (B_SZ * D_SZ)   // 16384

// ---------------------------------------------------------------------------
// GEMM: per output element, single sequential fmaf chain over k=0..511
// ascending, then + bias[e]. (Verified bit-exact vs harness ref previously.)
// 128x128 block tile, 8x8 per-thread microtile, interleaved lane mapping
// (m = ty + 16*i, n = tx + 16*j) so LDS reads are <=2-way bank conflicts.
// NEW: double-buffered LDS (ONE barrier per K-chunk, writes overlap compute)
// and bijective XCD-aware tile swizzle (4 n-tiles of an A-panel co-resident
// per XCD L2).
// ---------------------------------------------------------------------------
#define BM  128
#define BN  128
#define LDP 20    // padded LDS row stride in floats (80 B, 16B-aligned)

__global__ __launch_bounds__(256, 4) void gemm8x8_kernel(
    const float* __restrict__ A,     // [rows, 512]
    const float* __restrict__ W,     // [512, 512]
    const float* __restrict__ bias,  // [512]
    float* __restrict__ Y)           // [rows, 512]
{
#pragma clang fp contract(off)
  __shared__ float As[2][BM][LDP];   // 2 x 10240 B
  __shared__ float Bs[2][BN][LDP];   // 2 x 10240 B  -> 40960 B total

  const int tid = threadIdx.x;
  const int tx  = tid & 15;          // n-lane: n = tx + 16*j
  const int ty  = tid >> 4;          // m-lane: m = ty + 16*i

  // Bijective XCD swizzle: consecutive tiles on one XCD, n-fast so the 4
  // n-tiles sharing an A-row-panel are adjacent in time on the same L2.
  const int nwg  = (int)(gridDim.x * gridDim.y);
  const int orig = (int)(blockIdx.y * gridDim.x + blockIdx.x);
  const int q    = nwg >> 3, r = nwg & 7;
  const int xcd  = orig & 7, loc = orig >> 3;
  const int tix  = (xcd < r ? xcd * (q + 1) : r * (q + 1) + (xcd - r) * q) + loc;
  const int m0   = (tix >> 2) * BM;   // gridDim.y == 4 always (D_SZ/BN)
  const int n0   = (tix & 3) * BN;

  // staging: thread loads 2 float4 of A-tile and 2 of B-tile per chunk
  const int sr = tid >> 2;           // 0..63 tile row
  const int sq = (tid & 3) << 2;     // k-quad offset in floats

  const float* Ap0 = A + (size_t)(m0 + sr)      * D_SZ + sq;
  const float* Ap1 = A + (size_t)(m0 + 64 + sr) * D_SZ + sq;
  const float* Wp0 = W + (size_t)(n0 + sr)      * D_SZ + sq;
  const float* Wp1 = W + (size_t)(n0 + 64 + sr) * D_SZ + sq;

  float acc[8][8];
#pragma unroll
  for (int i = 0; i < 8; ++i)
#pragma unroll
    for (int j = 0; j < 8; ++j) acc[i][j] = 0.0f;

  // Prologue: chunk 0 -> LDS buf0; chunk 1 -> regs.
  float4 pa0 = *(const float4*)(Ap0);
  float4 pa1 = *(const float4*)(Ap1);
  float4 pb0 = *(const float4*)(Wp0);
  float4 pb1 = *(const float4*)(Wp1);
  *(float4*)&As[0][sr][sq]      = pa0;
  *(float4*)&As[0][64 + sr][sq] = pa1;
  *(float4*)&Bs[0][sr][sq]      = pb0;
  *(float4*)&Bs[0][64 + sr][sq] = pb1;
  pa0 = *(const float4*)(Ap0 + 16);
  pa1 = *(const float4*)(Ap1 + 16);
  pb0 = *(const float4*)(Wp0 + 16);
  pb1 = *(const float4*)(Wp1 + 16);
  __syncthreads();

  // One step: write chunk K0/16+1 (held in regs) into buf NXT, issue loads for
  // chunk K0/16+2, compute chunk K0/16 from buf CUR, single barrier.
#define GSTEP(CUR, NXT, K0)                                                    \
  {                                                                            \
    if ((K0) + 16 < D_SZ) {                                                    \
      *(float4*)&As[NXT][sr][sq]      = pa0;                                   \
      *(float4*)&As[NXT][64 + sr][sq] = pa1;                                   \
      *(float4*)&Bs[NXT][sr][sq]      = pb0;                                   \
      *(float4*)&Bs[NXT][64 + sr][sq] = pb1;                                   \
      if ((K0) + 32 < D_SZ) {                                                  \
        pa0 = *(const float4*)(Ap0 + (K0) + 32);                               \
        pa1 = *(const float4*)(Ap1 + (K0) + 32);                               \
        pb0 = *(const float4*)(Wp0 + (K0) + 32);                               \
        pb1 = *(const float4*)(Wp1 + (K0) + 32);                               \
      }                                                                        \
    }                                                                          \
    _Pragma("unroll")                                                          \
    for (int kq = 0; kq < 4; ++kq) {                                           \
      float4 b[8];                                                             \
      _Pragma("unroll")                                                        \
      for (int j = 0; j < 8; ++j)                                              \
        b[j] = *(const float4*)&Bs[CUR][tx + 16 * j][kq << 2];                 \
      _Pragma("unroll")                                                        \
      for (int i = 0; i < 8; ++i) {                                            \
        const float4 a = *(const float4*)&As[CUR][ty + 16 * i][kq << 2];       \
        _Pragma("unroll")                                                      \
        for (int j = 0; j < 8; ++j) {                                          \
          acc[i][j] = fmaf(a.x, b[j].x, acc[i][j]);                            \
          acc[i][j] = fmaf(a.y, b[j].y, acc[i][j]);                            \
          acc[i][j] = fmaf(a.z, b[j].z, acc[i][j]);                            \
          acc[i][j] = fmaf(a.w, b[j].w, acc[i][j]);                            \
        }                                                                      \
      }                                                                        \
    }                                                                          \
    __syncthreads();                                                           \
  }

#pragma unroll 1
  for (int k0 = 0; k0 < D_SZ; k0 += 32) {
    GSTEP(0, 1, k0)
    GSTEP(1, 0, k0 + 16)
  }
#undef GSTEP

#pragma unroll
  for (int i = 0; i < 8; ++i) {
    const int m = m0 + ty + 16 * i;
#pragma unroll
    for (int j = 0; j < 8; ++j) {
      const int n = n0 + tx + 16 * j;
      Y[(size_t)m * D_SZ + n] = acc[i][j] + bias[n];
    }
  }
}

// ---------------------------------------------------------------------------
// Scan phase 1: fwd and bwd LIF scans run concurrently (one kernel), spike
// bits packed 32-per-word into side buffers (no out read-modify-write).
//   v = v + (c - v)*0.5f;  s = (v - 1.0f) >= 0;  v = s ? 0 : v
// NEW: 2-deep register double-buffer (named ca/cb, compile-time indexed) so
// group g+1's 32 loads are in flight while group g's serial chain computes.
// ---------------------------------------------------------------------------
__global__ __launch_bounds__(64) void scan_dirs_kernel(
    const float* __restrict__ Y,
    uint32_t* __restrict__ bits_f,
    uint32_t* __restrict__ bits_b)
{
#pragma clang fp contract(off)
  const int blk = blockIdx.x;
  const bool fwd = blk < 256;
  const int idx = ((fwd ? blk : blk - 256) << 6) + threadIdx.x;
  float v = 0.0f;
  float ca[32], cb[32];

  if (fwd) {
#pragma unroll
    for (int j = 0; j < 32; ++j) ca[j] = Y[(size_t)j * BD + idx];
#pragma unroll 1
    for (int g = 0; g < 64; g += 2) {
#pragma unroll
      for (int j = 0; j < 32; ++j)
        cb[j] = Y[(size_t)((g + 1) * 32 + j) * BD + idx];
      uint32_t w = 0;
#pragma unroll
      for (int j = 0; j < 32; ++j) {
        v = v + (ca[j] - v) * 0.5f;
        const bool s = (v - 1.0f) >= 0.0f;
        w |= (uint32_t)s << j;
        v = s ? 0.0f : v;
      }
      bits_f[g * BD + idx] = w;
      if (g + 2 < 64) {
#pragma unroll
        for (int j = 0; j < 32; ++j)
          ca[j] = Y[(size_t)((g + 2) * 32 + j) * BD + idx];
      }
      w = 0;
#pragma unroll
      for (int j = 0; j < 32; ++j) {
        v = v + (cb[j] - v) * 0.5f;
        const bool s = (v - 1.0f) >= 0.0f;
        w |= (uint32_t)s << j;
        v = s ? 0.0f : v;
      }
      bits_f[(g + 1) * BD + idx] = w;
    }
  } else {
#pragma unroll
    for (int j = 0; j < 32; ++j) ca[j] = Y[(size_t)(63 * 32 + j) * BD + idx];
#pragma unroll 1
    for (int g = 63; g > 0; g -= 2) {
#pragma unroll
      for (int j = 0; j < 32; ++j)
        cb[j] = Y[(size_t)((g - 1) * 32 + j) * BD + idx];
      uint32_t w = 0;
#pragma unroll
      for (int j = 31; j >= 0; --j) {   // t descending overall
        v = v + (ca[j] - v) * 0.5f;
        const bool s = (v - 1.0f) >= 0.0f;
        w |= (uint32_t)s << j;
        v = s ? 0.0f : v;
      }
      bits_b[g * BD + idx] = w;
      if (g - 2 >= 0) {
#pragma unroll
        for (int j = 0; j < 32; ++j)
          ca[j] = Y[(size_t)((g - 2) * 32 + j) * BD + idx];
      }
      w = 0;
#pragma unroll
      for (int j = 31; j >= 0; --j) {
        v = v + (cb[j] - v) * 0.5f;
        const bool s = (v - 1.0f) >= 0.0f;
        w |= (uint32_t)s << j;
        v = s ? 0.0f : v;
      }
      bits_b[(g - 1) * BD + idx] = w;
    }
  }
}

// Scan phase 2: out[t,idx] = fwd_bit + bwd_bit.
// NEW: inverted loop — each thread reads ONE uint4 pair and emits all 32
// t-slices for its column quad (bit reads 268MB-of-L2 -> 16MB of HBM).
__global__ __launch_bounds__(256) void combine_kernel(
    const uint32_t* __restrict__ bf,
    const uint32_t* __restrict__ bb,
    float* __restrict__ out)
{
  const int gid = blockIdx.x * 256 + threadIdx.x;  // 0 .. 64*4096-1
  const int g   = gid >> 12;                       // bit-group (32 t's)
  const int i0  = (gid & 4095) << 2;               // column quad
  const uint4 wf = *(const uint4*)(bf + g * BD + i0);
  const uint4 wb = *(const uint4*)(bb + g * BD + i0);
#pragma unroll
  for (int bit = 0; bit < 32; ++bit) {
    float4 r;
    r.x = (float)(((wf.x >> bit) & 1u) + ((wb.x >> bit) & 1u));
    r.y = (float)(((wf.y >> bit) & 1u) + ((wb.y >> bit) & 1u));
    r.z = (float)(((wf.z >> bit) & 1u) + ((wb.z >> bit) & 1u));
    r.w = (float)(((wf.w >> bit) & 1u) + ((wb.w >> bit) & 1u));
    *(float4*)(out + (size_t)(g * 32 + bit) * BD + i0) = r;
  }
}

// ---------------------------------------------------------------------------
// Fallback scans (used only if ws is too small for the bit buffers).
// ---------------------------------------------------------------------------
__global__ __launch_bounds__(64) void lif_fwd_kernel(
    const float* __restrict__ Y, float* __restrict__ out,
    int tlen, float* __restrict__ vstate, int carry)
{
#pragma clang fp contract(off)
  const int idx = blockIdx.x * 64 + threadIdx.x;
  float v = carry ? vstate[idx] : 0.0f;
#pragma unroll 16
  for (int t = 0; t < tlen; ++t) {
    const float c = Y[(size_t)t * BD + idx];
    v = v + (c - v) * 0.5f;
    const bool s = (v - 1.0f) >= 0.0f;
    out[(size_t)t * BD + idx] = s ? 1.0f : 0.0f;
    v = s ? 0.0f : v;
  }
  vstate[idx] = v;
}

__global__ __launch_bounds__(64) void lif_bwd_kernel(
    const float* __restrict__ Y, float* __restrict__ out,
    int tlen, float* __restrict__ vstate, int carry)
{
#pragma clang fp contract(off)
  const int idx = blockIdx.x * 64 + threadIdx.x;
  float v = carry ? vstate[idx] : 0.0f;
#pragma unroll 16
  for (int tt = 0; tt < tlen; ++tt) {
    const size_t t = (size_t)(tlen - 1 - tt);
    const float c = Y[t * BD + idx];
    v = v + (c - v) * 0.5f;
    const bool s = (v - 1.0f) >= 0.0f;
    out[t * BD + idx] += s ? 1.0f : 0.0f;
    v = s ? 0.0f : v;
  }
  vstate[idx] = v;
}

// ---------------------------------------------------------------------------
extern "C" void kernel_launch(void* const* d_in, const int* in_sizes, int n_in,
                              void* d_out, int out_size, void* d_ws, size_t ws_size,
                              hipStream_t stream)
{
  const float* x = (const float*)d_in[0];   // [T, B, D]
  const float* W = (const float*)d_in[1];   // [D, D]
  const float* b = (const float*)d_in[2];   // [D]
  float* out = (float*)d_out;               // [T, B, D]

  const size_t full_bytes = (size_t)T_LEN * BD * sizeof(float);     // 134 MB
  const size_t bit_bytes  = (size_t)(T_LEN / 32) * BD * sizeof(uint32_t); // 4 MB
  const size_t vbytes     = (size_t)BD * sizeof(float);

  if (ws_size >= full_bytes + 2 * bit_bytes) {
    float*    Y  = (float*)d_ws;
    uint32_t* bf = (uint32_t*)((char*)d_ws + full_bytes);
    uint32_t* bb = (uint32_t*)((char*)d_ws + full_bytes + bit_bytes);
    dim3 grid(T_LEN * B_SZ / BM, D_SZ / BN);
    gemm8x8_kernel<<<grid, 256, 0, stream>>>(x, W, b, Y);
    scan_dirs_kernel<<<512, 64, 0, stream>>>(Y, bf, bb);
    combine_kernel<<<(T_LEN / 32) * (BD / 4) / 256, 256, 0, stream>>>(bf, bb, out);
  } else if (ws_size >= full_bytes + vbytes) {
    float* Y      = (float*)d_ws;
    float* vstate = (float*)((char*)d_ws + full_bytes);
    dim3 grid(T_LEN * B_SZ / BM, D_SZ / BN);
    gemm8x8_kernel<<<grid, 256, 0, stream>>>(x, W, b, Y);
    lif_fwd_kernel<<<BD / 64, 64, 0, stream>>>(Y, out, T_LEN, vstate, 0);
    lif_bwd_kernel<<<BD / 64, 64, 0, stream>>>(Y, out, T_LEN, vstate, 0);
  } else {
    // Chunked fallback; Tc a power-of-two divisor of T_LEN (>=4) so chunk
    // rows are a multiple of BM=128.
    const size_t avail = ws_size > vbytes ? ws_size - vbytes : 0;
    int Tc = T_LEN;
    while (Tc > 4 && (size_t)Tc * BD * sizeof(float) > avail) Tc >>= 1;
    float* Y      = (float*)d_ws;
    float* vstate = (float*)((char*)d_ws + (size_t)Tc * BD * sizeof(float));

    int first = 1;
    for (int t0 = 0; t0 < T_LEN; t0 += Tc) {
      dim3 grid(Tc * B_SZ / BM, D_SZ / BN);
      gemm8x8_kernel<<<grid, 256, 0, stream>>>(x + (size_t)t0 * BD, W, b, Y);
      lif_fwd_kernel<<<BD / 64, 64, 0, stream>>>(Y, out + (size_t)t0 * BD, Tc,
                                                 vstate, first ? 0 : 1);
      first = 0;
    }
    first = 1;
    for (int t0 = T_LEN - Tc; t0 >= 0; t0 -= Tc) {
      dim3 grid(Tc * B_SZ / BM, D_SZ / BN);
      gemm8x8_kernel<<<grid, 256, 0, stream>>>(x + (size_t)t0 * BD, W, b, Y);
      lif_bwd_kernel<<<BD / 64, 64, 0, stream>>>(Y, out + (size_t)t0 * BD, Tc,
                                                 vstate, first ? 0 : 1);
      first = 0;
    }
  }
}

// Round 2
// 906.816 us; speedup vs baseline: 5.4052x; 5.4052x over previous
//
#include <hip/hip_runtime.h>
#include <cstddef>
#include <cstdint>

// Shapes fixed by reference setup_inputs():
#define T_LEN 2048
#define B_SZ  32
#define D_SZ  512
#define BD    (B_SZ * D_SZ)   // 16384

// ---------------------------------------------------------------------------
// GEMM: per output element, single sequential fmaf chain over k=0..511
// ascending, then + bias[e]. (Verified bit-exact vs harness ref previously.)
// 128x128 block tile, 8x8 per-thread microtile, interleaved lane mapping
// (m = ty + 16*i, n = tx + 16*j) so LDS reads are <=2-way bank conflicts.
// Double-buffered LDS (ONE barrier per K-chunk, writes overlap compute)
// and bijective XCD-aware tile swizzle (4 n-tiles of an A-panel co-resident
// per XCD L2).
// NOTE: plain __launch_bounds__(256). The (256,4) variant clamped the
// allocator to 64 VGPRs -> acc[8][8] spilled to scratch (FETCH 6.1 GB,
// 8.5x regression). Do not re-add a min-waves bound here.
// ---------------------------------------------------------------------------
#define BM  128
#define BN  128
#define LDP 20    // padded LDS row stride in floats (80 B, 16B-aligned)

__global__ __launch_bounds__(256) void gemm8x8_kernel(
    const float* __restrict__ A,     // [rows, 512]
    const float* __restrict__ W,     // [512, 512]
    const float* __restrict__ bias,  // [512]
    float* __restrict__ Y)           // [rows, 512]
{
#pragma clang fp contract(off)
  __shared__ float As[2][BM][LDP];   // 2 x 10240 B
  __shared__ float Bs[2][BN][LDP];   // 2 x 10240 B  -> 40960 B total

  const int tid = threadIdx.x;
  const int tx  = tid & 15;          // n-lane: n = tx + 16*j
  const int ty  = tid >> 4;          // m-lane: m = ty + 16*i

  // Bijective XCD swizzle: consecutive tiles on one XCD, n-fast so the 4
  // n-tiles sharing an A-row-panel are adjacent in time on the same L2.
  const int nwg  = (int)(gridDim.x * gridDim.y);
  const int orig = (int)(blockIdx.y * gridDim.x + blockIdx.x);
  const int q    = nwg >> 3, r = nwg & 7;
  const int xcd  = orig & 7, loc = orig >> 3;
  const int tix  = (xcd < r ? xcd * (q + 1) : r * (q + 1) + (xcd - r) * q) + loc;
  const int m0   = (tix >> 2) * BM;   // gridDim.y == 4 always (D_SZ/BN)
  const int n0   = (tix & 3) * BN;

  // staging: thread loads 2 float4 of A-tile and 2 of B-tile per chunk
  const int sr = tid >> 2;           // 0..63 tile row
  const int sq = (tid & 3) << 2;     // k-quad offset in floats

  const float* Ap0 = A + (size_t)(m0 + sr)      * D_SZ + sq;
  const float* Ap1 = A + (size_t)(m0 + 64 + sr) * D_SZ + sq;
  const float* Wp0 = W + (size_t)(n0 + sr)      * D_SZ + sq;
  const float* Wp1 = W + (size_t)(n0 + 64 + sr) * D_SZ + sq;

  float acc[8][8];
#pragma unroll
  for (int i = 0; i < 8; ++i)
#pragma unroll
    for (int j = 0; j < 8; ++j) acc[i][j] = 0.0f;

  // Prologue: chunk 0 -> LDS buf0; chunk 1 -> regs.
  float4 pa0 = *(const float4*)(Ap0);
  float4 pa1 = *(const float4*)(Ap1);
  float4 pb0 = *(const float4*)(Wp0);
  float4 pb1 = *(const float4*)(Wp1);
  *(float4*)&As[0][sr][sq]      = pa0;
  *(float4*)&As[0][64 + sr][sq] = pa1;
  *(float4*)&Bs[0][sr][sq]      = pb0;
  *(float4*)&Bs[0][64 + sr][sq] = pb1;
  pa0 = *(const float4*)(Ap0 + 16);
  pa1 = *(const float4*)(Ap1 + 16);
  pb0 = *(const float4*)(Wp0 + 16);
  pb1 = *(const float4*)(Wp1 + 16);
  __syncthreads();

  // One step: write chunk K0/16+1 (held in regs) into buf NXT, issue loads for
  // chunk K0/16+2, compute chunk K0/16 from buf CUR, single barrier.
#define GSTEP(CUR, NXT, K0)                                                    \
  {                                                                            \
    if ((K0) + 16 < D_SZ) {                                                    \
      *(float4*)&As[NXT][sr][sq]      = pa0;                                   \
      *(float4*)&As[NXT][64 + sr][sq] = pa1;                                   \
      *(float4*)&Bs[NXT][sr][sq]      = pb0;                                   \
      *(float4*)&Bs[NXT][64 + sr][sq] = pb1;                                   \
      if ((K0) + 32 < D_SZ) {                                                  \
        pa0 = *(const float4*)(Ap0 + (K0) + 32);                               \
        pa1 = *(const float4*)(Ap1 + (K0) + 32);                               \
        pb0 = *(const float4*)(Wp0 + (K0) + 32);                               \
        pb1 = *(const float4*)(Wp1 + (K0) + 32);                               \
      }                                                                        \
    }                                                                          \
    _Pragma("unroll")                                                          \
    for (int kq = 0; kq < 4; ++kq) {                                           \
      float4 b[8];                                                             \
      _Pragma("unroll")                                                        \
      for (int j = 0; j < 8; ++j)                                              \
        b[j] = *(const float4*)&Bs[CUR][tx + 16 * j][kq << 2];                 \
      _Pragma("unroll")                                                        \
      for (int i = 0; i < 8; ++i) {                                            \
        const float4 a = *(const float4*)&As[CUR][ty + 16 * i][kq << 2];       \
        _Pragma("unroll")                                                      \
        for (int j = 0; j < 8; ++j) {                                          \
          acc[i][j] = fmaf(a.x, b[j].x, acc[i][j]);                            \
          acc[i][j] = fmaf(a.y, b[j].y, acc[i][j]);                            \
          acc[i][j] = fmaf(a.z, b[j].z, acc[i][j]);                            \
          acc[i][j] = fmaf(a.w, b[j].w, acc[i][j]);                            \
        }                                                                      \
      }                                                                        \
    }                                                                          \
    __syncthreads();                                                           \
  }

#pragma unroll 1
  for (int k0 = 0; k0 < D_SZ; k0 += 32) {
    GSTEP(0, 1, k0)
    GSTEP(1, 0, k0 + 16)
  }
#undef GSTEP

#pragma unroll
  for (int i = 0; i < 8; ++i) {
    const int m = m0 + ty + 16 * i;
#pragma unroll
    for (int j = 0; j < 8; ++j) {
      const int n = n0 + tx + 16 * j;
      Y[(size_t)m * D_SZ + n] = acc[i][j] + bias[n];
    }
  }
}

// ---------------------------------------------------------------------------
// Scan phase 1: fwd and bwd LIF scans run concurrently (one kernel), spike
// bits packed 32-per-word into side buffers (no out read-modify-write).
//   v = v + (c - v)*0.5f;  s = (v - 1.0f) >= 0;  v = s ? 0 : v
// 2-deep register double-buffer (named ca/cb, compile-time indexed) so
// group g+1's 32 loads are in flight while group g's serial chain computes.
// ---------------------------------------------------------------------------
__global__ __launch_bounds__(64) void scan_dirs_kernel(
    const float* __restrict__ Y,
    uint32_t* __restrict__ bits_f,
    uint32_t* __restrict__ bits_b)
{
#pragma clang fp contract(off)
  const int blk = blockIdx.x;
  const bool fwd = blk < 256;
  const int idx = ((fwd ? blk : blk - 256) << 6) + threadIdx.x;
  float v = 0.0f;
  float ca[32], cb[32];

  if (fwd) {
#pragma unroll
    for (int j = 0; j < 32; ++j) ca[j] = Y[(size_t)j * BD + idx];
#pragma unroll 1
    for (int g = 0; g < 64; g += 2) {
#pragma unroll
      for (int j = 0; j < 32; ++j)
        cb[j] = Y[(size_t)((g + 1) * 32 + j) * BD + idx];
      uint32_t w = 0;
#pragma unroll
      for (int j = 0; j < 32; ++j) {
        v = v + (ca[j] - v) * 0.5f;
        const bool s = (v - 1.0f) >= 0.0f;
        w |= (uint32_t)s << j;
        v = s ? 0.0f : v;
      }
      bits_f[g * BD + idx] = w;
      if (g + 2 < 64) {
#pragma unroll
        for (int j = 0; j < 32; ++j)
          ca[j] = Y[(size_t)((g + 2) * 32 + j) * BD + idx];
      }
      w = 0;
#pragma unroll
      for (int j = 0; j < 32; ++j) {
        v = v + (cb[j] - v) * 0.5f;
        const bool s = (v - 1.0f) >= 0.0f;
        w |= (uint32_t)s << j;
        v = s ? 0.0f : v;
      }
      bits_f[(g + 1) * BD + idx] = w;
    }
  } else {
#pragma unroll
    for (int j = 0; j < 32; ++j) ca[j] = Y[(size_t)(63 * 32 + j) * BD + idx];
#pragma unroll 1
    for (int g = 63; g > 0; g -= 2) {
#pragma unroll
      for (int j = 0; j < 32; ++j)
        cb[j] = Y[(size_t)((g - 1) * 32 + j) * BD + idx];
      uint32_t w = 0;
#pragma unroll
      for (int j = 31; j >= 0; --j) {   // t descending overall
        v = v + (ca[j] - v) * 0.5f;
        const bool s = (v - 1.0f) >= 0.0f;
        w |= (uint32_t)s << j;
        v = s ? 0.0f : v;
      }
      bits_b[g * BD + idx] = w;
      if (g - 2 >= 0) {
#pragma unroll
        for (int j = 0; j < 32; ++j)
          ca[j] = Y[(size_t)((g - 2) * 32 + j) * BD + idx];
      }
      w = 0;
#pragma unroll
      for (int j = 31; j >= 0; --j) {
        v = v + (cb[j] - v) * 0.5f;
        const bool s = (v - 1.0f) >= 0.0f;
        w |= (uint32_t)s << j;
        v = s ? 0.0f : v;
      }
      bits_b[(g - 1) * BD + idx] = w;
    }
  }
}

// Scan phase 2: out[t,idx] = fwd_bit + bwd_bit.
// Inverted loop — each thread reads ONE uint4 pair and emits all 32
// t-slices for its column quad (bit reads once from L2, writes coalesced).
__global__ __launch_bounds__(256) void combine_kernel(
    const uint32_t* __restrict__ bf,
    const uint32_t* __restrict__ bb,
    float* __restrict__ out)
{
  const int gid = blockIdx.x * 256 + threadIdx.x;  // 0 .. 64*4096-1
  const int g   = gid >> 12;                       // bit-group (32 t's)
  const int i0  = (gid & 4095) << 2;               // column quad
  const uint4 wf = *(const uint4*)(bf + g * BD + i0);
  const uint4 wb = *(const uint4*)(bb + g * BD + i0);
#pragma unroll
  for (int bit = 0; bit < 32; ++bit) {
    float4 r;
    r.x = (float)(((wf.x >> bit) & 1u) + ((wb.x >> bit) & 1u));
    r.y = (float)(((wf.y >> bit) & 1u) + ((wb.y >> bit) & 1u));
    r.z = (float)(((wf.z >> bit) & 1u) + ((wb.z >> bit) & 1u));
    r.w = (float)(((wf.w >> bit) & 1u) + ((wb.w >> bit) & 1u));
    *(float4*)(out + (size_t)(g * 32 + bit) * BD + i0) = r;
  }
}

// ---------------------------------------------------------------------------
// Fallback scans (used only if ws is too small for the bit buffers).
// ---------------------------------------------------------------------------
__global__ __launch_bounds__(64) void lif_fwd_kernel(
    const float* __restrict__ Y, float* __restrict__ out,
    int tlen, float* __restrict__ vstate, int carry)
{
#pragma clang fp contract(off)
  const int idx = blockIdx.x * 64 + threadIdx.x;
  float v = carry ? vstate[idx] : 0.0f;
#pragma unroll 16
  for (int t = 0; t < tlen; ++t) {
    const float c = Y[(size_t)t * BD + idx];
    v = v + (c - v) * 0.5f;
    const bool s = (v - 1.0f) >= 0.0f;
    out[(size_t)t * BD + idx] = s ? 1.0f : 0.0f;
    v = s ? 0.0f : v;
  }
  vstate[idx] = v;
}

__global__ __launch_bounds__(64) void lif_bwd_kernel(
    const float* __restrict__ Y, float* __restrict__ out,
    int tlen, float* __restrict__ vstate, int carry)
{
#pragma clang fp contract(off)
  const int idx = blockIdx.x * 64 + threadIdx.x;
  float v = carry ? vstate[idx] : 0.0f;
#pragma unroll 16
  for (int tt = 0; tt < tlen; ++tt) {
    const size_t t = (size_t)(tlen - 1 - tt);
    const float c = Y[t * BD + idx];
    v = v + (c - v) * 0.5f;
    const bool s = (v - 1.0f) >= 0.0f;
    out[t * BD + idx] += s ? 1.0f : 0.0f;
    v = s ? 0.0f : v;
  }
  vstate[idx] = v;
}

// ---------------------------------------------------------------------------
extern "C" void kernel_launch(void* const* d_in, const int* in_sizes, int n_in,
                              void* d_out, int out_size, void* d_ws, size_t ws_size,
                              hipStream_t stream)
{
  const float* x = (const float*)d_in[0];   // [T, B, D]
  const float* W = (const float*)d_in[1];   // [D, D]
  const float* b = (const float*)d_in[2];   // [D]
  float* out = (float*)d_out;               // [T, B, D]

  const size_t full_bytes = (size_t)T_LEN * BD * sizeof(float);     // 134 MB
  const size_t bit_bytes  = (size_t)(T_LEN / 32) * BD * sizeof(uint32_t); // 4 MB
  const size_t vbytes     = (size_t)BD * sizeof(float);

  if (ws_size >= full_bytes + 2 * bit_bytes) {
    float*    Y  = (float*)d_ws;
    uint32_t* bf = (uint32_t*)((char*)d_ws + full_bytes);
    uint32_t* bb = (uint32_t*)((char*)d_ws + full_bytes + bit_bytes);
    dim3 grid(T_LEN * B_SZ / BM, D_SZ / BN);
    gemm8x8_kernel<<<grid, 256, 0, stream>>>(x, W, b, Y);
    scan_dirs_kernel<<<512, 64, 0, stream>>>(Y, bf, bb);
    combine_kernel<<<(T_LEN / 32) * (BD / 4) / 256, 256, 0, stream>>>(bf, bb, out);
  } else if (ws_size >= full_bytes + vbytes) {
    float* Y      = (float*)d_ws;
    float* vstate = (float*)((char*)d_ws + full_bytes);
    dim3 grid(T_LEN * B_SZ / BM, D_SZ / BN);
    gemm8x8_kernel<<<grid, 256, 0, stream>>>(x, W, b, Y);
    lif_fwd_kernel<<<BD / 64, 64, 0, stream>>>(Y, out, T_LEN, vstate, 0);
    lif_bwd_kernel<<<BD / 64, 64, 0, stream>>>(Y, out, T_LEN, vstate, 0);
  } else {
    // Chunked fallback; Tc a power-of-two divisor of T_LEN (>=4) so chunk
    // rows are a multiple of BM=128.
    const size_t avail = ws_size > vbytes ? ws_size - vbytes : 0;
    int Tc = T_LEN;
    while (Tc > 4 && (size_t)Tc * BD * sizeof(float) > avail) Tc >>= 1;
    float* Y      = (float*)d_ws;
    float* vstate = (float*)((char*)d_ws + (size_t)Tc * BD * sizeof(float));

    int first = 1;
    for (int t0 = 0; t0 < T_LEN; t0 += Tc) {
      dim3 grid(Tc * B_SZ / BM, D_SZ / BN);
      gemm8x8_kernel<<<grid, 256, 0, stream>>>(x + (size_t)t0 * BD, W, b, Y);
      lif_fwd_kernel<<<BD / 64, 64, 0, stream>>>(Y, out + (size_t)t0 * BD, Tc,
                                                 vstate, first ? 0 : 1);
      first = 0;
    }
    first = 1;
    for (int t0 = T_LEN - Tc; t0 >= 0; t0 -= Tc) {
      dim3 grid(Tc * B_SZ / BM, D_SZ / BN);
      gemm8x8_kernel<<<grid, 256, 0, stream>>>(x + (size_t)t0 * BD, W, b, Y);
      lif_bwd_kernel<<<BD / 64, 64, 0, stream>>>(Y, out + (size_t)t0 * BD, Tc,
                                                 vstate, first ? 0 : 1);
      first = 0;
    }
  }
}